// Round 3
// baseline (982.758 us; speedup 1.0000x reference)
//
#include <hip/hip_runtime.h>

typedef unsigned short u16;
typedef __attribute__((ext_vector_type(8))) short s8v;   // 8 bf16 (4 VGPRs) — MFMA A/B frag
typedef __attribute__((ext_vector_type(4))) float f4v;   // 4 fp32 — MFMA C/D frag

#define NN 16384
#define EE 262144
#define ET (EE + NN)      // 278528 = 4352 * 64
#define NTILES (ET / 64)  // 4352

__device__ __forceinline__ float bfu(u16 h){ return __uint_as_float((unsigned)h << 16); }
__device__ __forceinline__ u16 f2bf(float f){
  unsigned u = __float_as_uint(f);
  unsigned r = u + 0x7FFFu + ((u >> 16) & 1u);   // RNE
  return (u16)(r >> 16);
}
__device__ __forceinline__ float ldf(const void* p, size_t i, int isbf){
  return isbf ? bfu(((const u16*)p)[i]) : ((const float*)p)[i];
}
__device__ __forceinline__ float gelu_f(float x){ return 0.5f*x*(1.0f+erff(x*0.7071067811865475f)); }

__device__ __forceinline__ uint4 load8bf(const void* p, size_t eoff, int isbf){
  if (isbf) return *(const uint4*)((const u16*)p + eoff);
  const float* f = (const float*)p + eoff;
  uint4 r;
  r.x = (unsigned)f2bf(f[0]) | ((unsigned)f2bf(f[1])<<16);
  r.y = (unsigned)f2bf(f[2]) | ((unsigned)f2bf(f[3])<<16);
  r.z = (unsigned)f2bf(f[4]) | ((unsigned)f2bf(f[5])<<16);
  r.w = (unsigned)f2bf(f[6]) | ((unsigned)f2bf(f[7])<<16);
  return r;
}

// ---------------- dtype detector ----------------
__global__ void k_detect(const void* nf, int* flag)
{
  int t = threadIdx.x;
  const float* f = (const float*)nf;
  int cnt = 0;
  for (int i = t; i < 4096; i += 256) {
    float a = fabsf(f[i]);
    if (a > 1e-5f && a < 100.0f) cnt++;   // NaN compares false
  }
  __shared__ int s[256];
  s[t] = cnt; __syncthreads();
  for (int st = 128; st > 0; st >>= 1) { if (t < st) s[t] += s[t+st]; __syncthreads(); }
  if (t == 0) *flag = (s[0] < 2048) ? 1 : 0;
}

// ---------------- bf16 conversion of node_feats ----------------
__global__ void k_cvt(const void* __restrict__ in, u16* __restrict__ out, const int* __restrict__ dflag)
{
  int isbf = *dflag;
  size_t i = ((size_t)blockIdx.x*256 + threadIdx.x)*8;
  *(uint4*)&out[i] = load8bf(in, i, isbf);
}

// ---------------- whole-K-in-LDS GEMM: C[M,N] = A(bf16) @ B^T, barrier-free K loop ----------------
// Block: 4 waves side-by-side (256 cols), MF*16 rows. A-tile [MF*16][KK] staged once:
// LINEAR LDS dest + pre-swizzled global source (rule #21), so reads at byte^((row&7)<<4)
// see LDS[f(c)]=global[c] (conflict-free ds_read_b128). B frags loaded per k-step straight
// from global (L2-resident weights). CFMT: 0 fp32 C, 1 bf16 C, 2 both (C fp32 + C2 bf16).
template<int KK, int MF, int ACT, int CFMT>
__global__ __launch_bounds__(256)
void mg2(const u16* __restrict__ A,
         const void* __restrict__ B1, size_t b1off,
         const void* __restrict__ B2, size_t b2off, int nsplit,
         const void* __restrict__ bias1, const void* __restrict__ bias2,
         size_t bioff, int has_bias,
         void* __restrict__ C, void* __restrict__ C2, int N,
         const int* __restrict__ dflag)
{
  constexpr int ROWS = MF*16;
  constexpr int CPR  = KK/8;          // 16B chunks per A row
  constexpr int IT   = ROWS*CPR/256;  // staging chunks per thread
  __shared__ u16 As[ROWS*KK];

  int isbf = *dflag;
  int t = threadIdx.x;
  int w = t>>6, lane = t&63, l4 = lane&15, quad = lane>>4;
  int bm = blockIdx.y*ROWS, bn = blockIdx.x*256;

  // ---- stage whole-K A tile: linear LDS dest, pre-swizzled global src ----
  const u16* Abase = A + (size_t)bm*KK;
  uint4 stg[IT];
  #pragma unroll
  for (int it=0; it<IT; ++it) {
    int c = it*256 + t;
    int gc = c ^ ((c/CPR)&7);                    // f(c): row-preserving involution
    stg[it] = *(const uint4*)(Abase + (size_t)gc*8);
  }
  #pragma unroll
  for (int it=0; it<IT; ++it) {
    int c = it*256 + t;
    *(uint4*)((char*)As + (size_t)c*16) = stg[it];   // LDS[c] = global[f(c)]  =>  LDS[f(c')] = global[c']
  }
  __syncthreads();

  // ---- per-j B pointers (k-invariant) ----
  const void* Bp[4]; size_t Be[4]; int colj[4];
  #pragma unroll
  for (int j=0;j<4;++j) {
    int cj = bn + w*64 + j*16 + l4;
    colj[j] = cj;
    if (cj < nsplit) { Bp[j] = B1; Be[j] = b1off + (size_t)cj*KK; }
    else             { Bp[j] = B2; Be[j] = b2off + (size_t)(cj-nsplit)*KK; }
  }

  f4v zero = {0.f,0.f,0.f,0.f};
  f4v acc[MF][4];
  #pragma unroll
  for (int i=0;i<MF;i++)
    #pragma unroll
    for (int j=0;j<4;j++) acc[i][j] = zero;

  #pragma unroll
  for (int s=0; s<KK/32; ++s) {
    s8v b[4];
    #pragma unroll
    for (int j=0;j<4;++j) {
      uint4 bv = load8bf(Bp[j], Be[j] + s*32 + quad*8, isbf);
      b[j] = *(s8v*)&bv;
    }
    s8v a[MF];
    #pragma unroll
    for (int i=0;i<MF;++i) {
      int row = i*16 + l4;
      int byte = (row*(KK*2) + s*64 + quad*16) ^ ((row&7)<<4);
      a[i] = *(const s8v*)((const char*)As + byte);
    }
    #pragma unroll
    for (int i=0;i<MF;++i)
      #pragma unroll
      for (int j=0;j<4;++j)
        acc[i][j] = __builtin_amdgcn_mfma_f32_16x16x32_bf16(a[i], b[j], acc[i][j], 0,0,0);
  }

  // ---- epilogue ----
  #pragma unroll
  for (int i=0;i<MF;++i)
    #pragma unroll
    for (int j=0;j<4;++j) {
      int cj = colj[j];
      float bvs = 0.f;
      if (has_bias) bvs = (cj < nsplit) ? ldf(bias1, bioff + cj, isbf)
                                        : ldf(bias2, bioff + cj - nsplit, isbf);
      #pragma unroll
      for (int r=0;r<4;++r) {
        int row = bm + i*16 + quad*4 + r;
        float v = acc[i][j][r] + bvs;
        if (ACT==1) v = gelu_f(v);
        if (CFMT==1) ((u16*)C)[(size_t)row*N + cj] = f2bf(v);
        else {
          ((float*)C)[(size_t)row*N + cj] = v;
          if (CFMT==2) ((u16*)C2)[(size_t)row*N + cj] = f2bf(v);
        }
      }
    }
}

// ---------------- CSR build ----------------
__global__ void k_count(const int* __restrict__ dst, int* __restrict__ deg)
{
  int e = blockIdx.x*256 + threadIdx.x;
  if (e >= ET) return;
  int d = (e < EE) ? dst[e] : (e - EE);
  atomicAdd(&deg[d], 1);
}

__global__ void k_scan(const int* __restrict__ deg, int* __restrict__ rowstart)
{
  __shared__ int csum[256];
  int t = threadIdx.x;
  int s = 0;
  for (int i=0;i<64;i++) s += deg[t*64+i];
  csum[t] = s;
  __syncthreads();
  if (t == 0) {
    int r = 0;
    for (int i=0;i<256;i++){ int v = csum[i]; csum[i] = r; r += v; }
    rowstart[NN] = r;
  }
  __syncthreads();
  int b = csum[t];
  for (int i=0;i<64;i++){ rowstart[t*64+i] = b; b += deg[t*64+i]; }
}

// also emit src/dst per CSR slot so hot kernels skip the csr->edge_index indirection
__global__ void k_scatter(const int* __restrict__ src, const int* __restrict__ dst,
                          const int* __restrict__ rowstart,
                          int* __restrict__ fill, int* __restrict__ csr,
                          int* __restrict__ srcc, int* __restrict__ dstc)
{
  int e = blockIdx.x*256 + threadIdx.x;
  if (e >= ET) return;
  int d  = (e < EE) ? dst[e] : (e - EE);
  int sv = (e < EE) ? src[e] : (e - EE);
  int pos = rowstart[d] + atomicAdd(&fill[d], 1);
  csr[pos]  = e;
  srcc[pos] = sv;
  dstc[pos] = d;
}

__global__ void k_loopmean(const int* __restrict__ csr, const int* __restrict__ rowstart,
                           const void* __restrict__ edge_attr, u16* __restrict__ loopmean,
                           const int* __restrict__ dflag)
{
  int isbf = *dflag;
  int n = blockIdx.x, j = threadIdx.x;   // 64 threads
  int s = rowstart[n], e1 = rowstart[n+1];
  float sum = 0.f; int cnt = 0;
  for (int p = s; p < e1; ++p) {
    int eid = csr[p];
    if (eid < EE) { sum += ldf(edge_attr, (size_t)eid*64 + j, isbf); cnt++; }
  }
  loopmean[(size_t)n*64 + j] = f2bf(sum / (float)max(cnt, 1));
}

// Wc[l] = lin_edge_w[l] ([256,128]) @ init_edge_w ([128,64]) -> [L,256,64] bf16
__global__ void k_wc(const void* __restrict__ We, const void* __restrict__ iew,
                     u16* __restrict__ Wcb, const int* __restrict__ dflag)
{
  int isbf = *dflag;
  int idx = blockIdx.x*256 + threadIdx.x;    // 32768
  int j = idx & 63, c = (idx >> 6) & 255, l = idx >> 14;
  float s = 0.f;
  for (int k=0;k<128;k++) s += ldf(We, ((size_t)l*256 + c)*128 + k, isbf) * ldf(iew, (size_t)k*64 + j, isbf);
  Wcb[idx] = f2bf(s);
}

// ---------------- edge-parallel logits in CSR (dst-sorted) order ----------------
__global__ __launch_bounds__(256)
void k_elogits(const int* __restrict__ csr, const int* __restrict__ srcc, const int* __restrict__ dstc,
               const u16* __restrict__ Wcb, const u16* __restrict__ xlr,
               const void* __restrict__ edge_attr, const u16* __restrict__ loopmean,
               const void* __restrict__ att, size_t att_off,
               float* __restrict__ logits, const int* __restrict__ dflag)
{
  int isbf = *dflag;
  __shared__ u16 WcF[32*64*8];    // 32 A-frags x 64 lanes x 8 bf16 (frag-order, conflict-free b128)
  __shared__ u16 attr_s[64*72];   // 64 edges x 64ch, stride 72
  __shared__ float satt[256];
  __shared__ int ssrc[64], sdst[64];

  int t = threadIdx.x;
  int w = t>>6, lane = t&63, l4 = lane&15, quad = lane>>4;

  satt[t] = ldf(att, att_off + t, isbf);
  #pragma unroll
  for (int f = 0; f < 8; ++f) {
    int fr = w + f*4;              // 0..31
    int i = fr >> 1, ks = fr & 1;
    *(uint4*)&WcF[(fr*64 + lane)*8] = *(const uint4*)&Wcb[(size_t)(16*i + l4)*64 + ks*32 + quad*8];
  }

  f4v zero = {0.f,0.f,0.f,0.f};
  for (int tile = blockIdx.x; tile < NTILES; tile += gridDim.x) {
    int e0 = tile*64;              // CSR position base
    __syncthreads();
    if (t < 64) {
      ssrc[t] = srcc[e0 + t];
      sdst[t] = dstc[e0 + t];
    }
    {
      int er = t >> 2, part = t & 3;
      int eid = csr[e0 + er];      // 4 threads/edge -> broadcast load
      uint4 v0, v1;
      if (eid < EE) {
        v0 = load8bf(edge_attr, (size_t)eid*64 + part*16,     isbf);
        v1 = load8bf(edge_attr, (size_t)eid*64 + part*16 + 8, isbf);
      } else {
        v0 = *(const uint4*)&loopmean[(size_t)(eid-EE)*64 + part*16];
        v1 = *(const uint4*)&loopmean[(size_t)(eid-EE)*64 + part*16 + 8];
      }
      *(uint4*)&attr_s[er*72 + part*16]     = v0;
      *(uint4*)&attr_s[er*72 + part*16 + 8] = v1;
    }
    __syncthreads();

    s8v b0 = *(const s8v*)&attr_s[(w*16 + l4)*72 + quad*8];
    s8v b1 = *(const s8v*)&attr_s[(w*16 + l4)*72 + 32 + quad*8];
    f4v acc[16];
    #pragma unroll
    for (int i=0;i<16;++i){
      s8v a0 = *(const s8v*)&WcF[((2*i  )*64 + lane)*8];
      s8v a1 = *(const s8v*)&WcF[((2*i+1)*64 + lane)*8];
      acc[i] = __builtin_amdgcn_mfma_f32_16x16x32_bf16(a0, b0, zero, 0,0,0);
      acc[i] = __builtin_amdgcn_mfma_f32_16x16x32_bf16(a1, b1, acc[i], 0,0,0);
    }

    int me = w*16 + l4;
    int sn = ssrc[me], dn = sdst[me];
    float ph[8] = {0.f,0.f,0.f,0.f,0.f,0.f,0.f,0.f};
    #pragma unroll
    for (int i=0;i<16;++i){
      uint2 xlv = *(const uint2*)&xlr[(size_t)sn*512 +       i*16 + quad*4];
      uint2 xrv = *(const uint2*)&xlr[(size_t)dn*512 + 256 + i*16 + quad*4];
      float4 av = *(const float4*)&satt[i*16 + quad*4];
      float m0 = acc[i][0] + bfu((u16)(xlv.x & 0xffff)) + bfu((u16)(xrv.x & 0xffff));
      float m1 = acc[i][1] + bfu((u16)(xlv.x >> 16))    + bfu((u16)(xrv.x >> 16));
      float m2 = acc[i][2] + bfu((u16)(xlv.y & 0xffff)) + bfu((u16)(xrv.y & 0xffff));
      float m3 = acc[i][3] + bfu((u16)(xlv.y >> 16))    + bfu((u16)(xrv.y >> 16));
      float g0 = fmaxf(m0, 0.2f*m0), g1 = fmaxf(m1, 0.2f*m1);
      float g2 = fmaxf(m2, 0.2f*m2), g3 = fmaxf(m3, 0.2f*m3);
      ph[i>>1] += av.x*g0 + av.y*g1 + av.z*g2 + av.w*g3;
    }
    #pragma unroll
    for (int h=0;h<8;++h){
      ph[h] += __shfl_xor(ph[h], 16);
      ph[h] += __shfl_xor(ph[h], 32);
    }
    if (quad == 0){
      float4 lo = {ph[0], ph[1], ph[2], ph[3]};
      float4 hi = {ph[4], ph[5], ph[6], ph[7]};
      *(float4*)&logits[(size_t)(e0 + me)*8]     = lo;
      *(float4*)&logits[(size_t)(e0 + me)*8 + 4] = hi;
    }
  }
}

// ---------------- one wave per node: online softmax + aggregate + bias + residual + LN1 ----------------
__global__ __launch_bounds__(256)
void k_aggln(const int* __restrict__ srcc, const int* __restrict__ rowstart,
             const float* __restrict__ logits, const u16* __restrict__ xlr, const float* __restrict__ xbuf,
             const void* __restrict__ gat_bias, const void* __restrict__ ln1g, const void* __restrict__ ln1b,
             size_t poff, float* __restrict__ hbuf, u16* __restrict__ hbufb, const int* __restrict__ dflag)
{
  int isbf = *dflag;
  int lane = threadIdx.x & 63, wid = threadIdx.x >> 6;
  int n = blockIdx.x*4 + wid;
  int s = rowstart[n], deg = rowstart[n+1] - s;
  int myh = lane >> 3;                       // head of channels 4*lane..4*lane+3
  float mrun = -3.0e38f, lrun = 0.f;
  float a0=0.f, a1=0.f, a2=0.f, a3=0.f;

  for (int c0 = 0; c0 < deg; c0 += 64) {
    int idx = s + c0 + lane; if (idx >= ET) idx = ET-1;
    int sv = srcc[idx];
    int lim = min(64, deg - c0);
    size_t lbase = (size_t)(s + c0)*8 + myh;
    for (int j = 0; j < lim; ++j) {
      int sn  = __shfl(sv, j);
      float lg = logits[lbase + (size_t)j*8];
      uint2 xv = *(const uint2*)&xlr[(size_t)sn*512 + 4*lane];
      float mn = fmaxf(mrun, lg);
      float sc = __expf(mrun - mn);
      float wv = __expf(lg - mn);
      mrun = mn;
      lrun = lrun*sc + wv;
      a0 = a0*sc + wv*bfu((u16)(xv.x & 0xffff));
      a1 = a1*sc + wv*bfu((u16)(xv.x >> 16));
      a2 = a2*sc + wv*bfu((u16)(xv.y & 0xffff));
      a3 = a3*sc + wv*bfu((u16)(xv.y >> 16));
    }
  }
  float inv = 1.f/(lrun + 1e-16f);
  int c = 4*lane;
  float4 res = *(const float4*)&xbuf[(size_t)n*256 + c];
  float o0 = a0*inv + ldf(gat_bias, poff+c+0, isbf) + res.x;
  float o1 = a1*inv + ldf(gat_bias, poff+c+1, isbf) + res.y;
  float o2 = a2*inv + ldf(gat_bias, poff+c+2, isbf) + res.z;
  float o3 = a3*inv + ldf(gat_bias, poff+c+3, isbf) + res.w;

  float v = o0+o1+o2+o3;
  #pragma unroll
  for (int off=1; off<64; off<<=1) v += __shfl_xor(v, off);
  float mu = v * (1.f/256.f);
  float d0=o0-mu, d1=o1-mu, d2=o2-mu, d3=o3-mu;
  float v2 = d0*d0+d1*d1+d2*d2+d3*d3;
  #pragma unroll
  for (int off=1; off<64; off<<=1) v2 += __shfl_xor(v2, off);
  float wn = rsqrtf(v2*(1.f/256.f) + 1e-5f);
  float4 outv;
  outv.x = d0*wn*ldf(ln1g, poff+c+0, isbf) + ldf(ln1b, poff+c+0, isbf);
  outv.y = d1*wn*ldf(ln1g, poff+c+1, isbf) + ldf(ln1b, poff+c+1, isbf);
  outv.z = d2*wn*ldf(ln1g, poff+c+2, isbf) + ldf(ln1b, poff+c+2, isbf);
  outv.w = d3*wn*ldf(ln1g, poff+c+3, isbf) + ldf(ln1b, poff+c+3, isbf);
  *(float4*)&hbuf[(size_t)n*256 + c] = outv;
  uint2 hb;
  hb.x = (unsigned)f2bf(outv.x) | ((unsigned)f2bf(outv.y)<<16);
  hb.y = (unsigned)f2bf(outv.z) | ((unsigned)f2bf(outv.w)<<16);
  *(uint2*)&hbufb[(size_t)n*256 + c] = hb;
}

// ---------------- residual + LN2 -> xbuf (fp32 + bf16) ----------------
__global__ __launch_bounds__(256)
void k_ln_add(const float* __restrict__ a, const u16* __restrict__ b2,
              const void* __restrict__ gg, const void* __restrict__ bb, size_t poff,
              float* __restrict__ out, u16* __restrict__ outb, const int* __restrict__ dflag)
{
  int isbf = *dflag;
  int n = blockIdx.x, t = threadIdx.x;
  __shared__ float r[256];
  float x = a[(size_t)n*256 + t] + bfu(b2[(size_t)n*256 + t]);
  r[t] = x; __syncthreads();
  for (int st = 128; st > 0; st >>= 1) { if (t < st) r[t] += r[t+st]; __syncthreads(); }
  float mu = r[0] * (1.f/256.f);
  __syncthreads();
  float d = x - mu;
  r[t] = d*d; __syncthreads();
  for (int st = 128; st > 0; st >>= 1) { if (t < st) r[t] += r[t+st]; __syncthreads(); }
  float var = r[0] * (1.f/256.f);
  float o = d * rsqrtf(var + 1e-5f) * ldf(gg, poff + t, isbf) + ldf(bb, poff + t, isbf);
  out[(size_t)n*256 + t] = o;
  outb[(size_t)n*256 + t] = f2bf(o);
}

__global__ void k_out(const float* __restrict__ x, void* __restrict__ out, const int* __restrict__ dflag)
{
  int isbf = *dflag;
  int i = blockIdx.x*256 + threadIdx.x;
  if (isbf) ((u16*)out)[i] = f2bf(x[i]);
  else      ((float*)out)[i] = x[i];
}

extern "C" void kernel_launch(void* const* d_in, const int* in_sizes, int n_in,
                              void* d_out, int out_size, void* d_ws, size_t ws_size,
                              hipStream_t stream)
{
  const void* node_feats = d_in[0];
  const int*  edge_index = (const int*)d_in[1];
  const void* edge_attr  = d_in[2];
  const void* init_node_w= d_in[3];
  const void* init_edge_w= d_in[4];
  const void* lin_l_w    = d_in[5];
  const void* lin_l_b    = d_in[6];
  const void* lin_r_w    = d_in[7];
  const void* lin_r_b    = d_in[8];
  const void* lin_edge_w = d_in[9];
  const void* att        = d_in[10];
  const void* gat_bias   = d_in[11];
  const void* ln1_g      = d_in[12];
  const void* ln1_b      = d_in[13];
  const void* mlp_w1     = d_in[14];
  const void* mlp_w2     = d_in[15];
  const void* ln2_g      = d_in[16];
  const void* ln2_b      = d_in[17];

  const int* srcp = edge_index;
  const int* dstp = edge_index + EE;

  char* p = (char*)d_ws;
  auto alloc = [&](size_t bytes) { void* r = (void*)p; p += (bytes + 255) & ~(size_t)255; return r; };
  int*   dflag   = (int*)alloc(256);
  int*   deg     = (int*)alloc((size_t)NN*4);
  int*   rowstart= (int*)alloc((size_t)(NN+1)*4);
  int*   fill    = (int*)alloc((size_t)NN*4);
  int*   csr     = (int*)alloc((size_t)ET*4);
  int*   srcc    = (int*)alloc((size_t)ET*4);
  int*   dstc    = (int*)alloc((size_t)ET*4);
  u16*   Wcb     = (u16*)alloc((size_t)2*256*64*2);
  u16*   loopmean= (u16*)alloc((size_t)NN*64*2);
  // logits + hbuf allocated contiguously; nfb (24 MB, init-only) aliases their span
  float* logits  = (float*)alloc((size_t)ET*8*4);           // 8.9 MB
  float* hbuf    = (float*)alloc((size_t)NN*256*4);         // 16 MB
  float* xbuf    = (float*)alloc((size_t)NN*256*4);
  u16*   xbufb   = (u16*)alloc((size_t)NN*256*2);
  u16*   hbufb   = (u16*)alloc((size_t)NN*256*2);
  u16*   xlr     = (u16*)alloc((size_t)NN*512*2);  // xl = cols 0..255, xr = cols 256..511
  u16*   nfb     = (u16*)logits;    // [NN,768] bf16, dead before logits/hbuf are written
  u16*   ymid    = xlr;             // [NN,512] bf16 alias (xlr dead at MLP time)
  u16*   y2      = (u16*)d_out;     // bf16 scratch; final k_out overwrites

  hipMemsetAsync(deg,  0, (size_t)NN*4, stream);
  hipMemsetAsync(fill, 0, (size_t)NN*4, stream);

  k_detect <<<1, 256, 0, stream>>>(node_feats, dflag);

  k_count  <<<(ET+255)/256, 256, 0, stream>>>(dstp, deg);
  k_scan   <<<1, 256, 0, stream>>>(deg, rowstart);
  k_scatter<<<(ET+255)/256, 256, 0, stream>>>(srcp, dstp, rowstart, fill, csr, srcc, dstc);
  k_loopmean<<<NN, 64, 0, stream>>>(csr, rowstart, edge_attr, loopmean, dflag);
  k_wc     <<<128, 256, 0, stream>>>(lin_edge_w, init_edge_w, Wcb, dflag);

  // node_feats -> bf16
  k_cvt<<<(NN*768)/(8*256), 256, 0, stream>>>(node_feats, nfb, dflag);
  // x = node_feats @ init_node_w.T  (fp32 xbuf + bf16 xbufb)
  mg2<768,2,0,2><<<dim3(1, NN/32), 256, 0, stream>>>(nfb, init_node_w, 0, init_node_w, 0, 1<<29,
                                                     nullptr, nullptr, 0, 0, xbuf, xbufb, 256, dflag);

  for (int l = 0; l < 2; ++l) {
    size_t wo = (size_t)l*256*256;
    size_t bo = (size_t)l*256;
    // xlr = [x@Wl^T + bl | x@Wr^T + br]  (dual-B, N=512)
    mg2<256,4,0,1><<<dim3(2, NN/64), 256, 0, stream>>>(xbufb, lin_l_w, wo, lin_r_w, wo, 256,
                                                       lin_l_b, lin_r_b, bo, 1, xlr, nullptr, 512, dflag);
    k_elogits<<<768, 256, 0, stream>>>(csr, srcc, dstc, Wcb + (size_t)l*256*64, xlr,
                                       edge_attr, loopmean, att, (size_t)l*256, logits, dflag);
    k_aggln<<<NN/4, 256, 0, stream>>>(srcc, rowstart, logits, xlr, xbuf,
                                      gat_bias, ln1_g, ln1_b, bo, hbuf, hbufb, dflag);
    mg2<256,4,1,1><<<dim3(2, NN/64), 256, 0, stream>>>(hbufb, mlp_w1, (size_t)l*512*256, mlp_w1, 0, 1<<29,
                                                       nullptr, nullptr, 0, 0, ymid, nullptr, 512, dflag);
    mg2<512,4,0,1><<<dim3(1, NN/64), 256, 0, stream>>>(ymid, mlp_w2, (size_t)l*256*512, mlp_w2, 0, 1<<29,
                                                       nullptr, nullptr, 0, 0, y2, nullptr, 256, dflag);
    k_ln_add<<<NN, 256, 0, stream>>>(hbuf, y2, ln2_g, ln2_b, bo, xbuf, xbufb, dflag);
  }

  k_out<<<(NN*256)/256, 256, 0, stream>>>(xbuf, d_out, dflag);
}

// Round 4
// 634.568 us; speedup vs baseline: 1.5487x; 1.5487x over previous
//
#include <hip/hip_runtime.h>

typedef unsigned short u16;
typedef __attribute__((ext_vector_type(8))) short s8v;   // 8 bf16 (4 VGPRs) — MFMA A/B frag
typedef __attribute__((ext_vector_type(4))) float f4v;   // 4 fp32 — MFMA C/D frag

#define NN 16384
#define EE 262144
#define ET (EE + NN)      // 278528 = 4352 * 64
#define NTILES (ET / 64)  // 4352

__device__ __forceinline__ float bfu(u16 h){ return __uint_as_float((unsigned)h << 16); }
__device__ __forceinline__ u16 f2bf(float f){
  unsigned u = __float_as_uint(f);
  unsigned r = u + 0x7FFFu + ((u >> 16) & 1u);   // RNE
  return (u16)(r >> 16);
}
__device__ __forceinline__ float ldf(const void* p, size_t i, int isbf){
  return isbf ? bfu(((const u16*)p)[i]) : ((const float*)p)[i];
}
__device__ __forceinline__ float gelu_f(float x){ return 0.5f*x*(1.0f+erff(x*0.7071067811865475f)); }

__device__ __forceinline__ uint4 load8bf(const void* p, size_t eoff, int isbf){
  if (isbf) return *(const uint4*)((const u16*)p + eoff);
  const float* f = (const float*)p + eoff;
  uint4 r;
  r.x = (unsigned)f2bf(f[0]) | ((unsigned)f2bf(f[1])<<16);
  r.y = (unsigned)f2bf(f[2]) | ((unsigned)f2bf(f[3])<<16);
  r.z = (unsigned)f2bf(f[4]) | ((unsigned)f2bf(f[5])<<16);
  r.w = (unsigned)f2bf(f[6]) | ((unsigned)f2bf(f[7])<<16);
  return r;
}

// async global->LDS, 16B per lane; LDS dest = wave-uniform base + lane*16
__device__ __forceinline__ void gload16(const void* g, void* l){
  __builtin_amdgcn_global_load_lds((const __attribute__((address_space(1))) void*)g,
                                   (__attribute__((address_space(3))) void*)l, 16, 0, 0);
}

// ---------------- dtype detector ----------------
__global__ void k_detect(const void* nf, int* flag)
{
  int t = threadIdx.x;
  const float* f = (const float*)nf;
  int cnt = 0;
  for (int i = t; i < 4096; i += 256) {
    float a = fabsf(f[i]);
    if (a > 1e-5f && a < 100.0f) cnt++;   // NaN compares false
  }
  __shared__ int s[256];
  s[t] = cnt; __syncthreads();
  for (int st = 128; st > 0; st >>= 1) { if (t < st) s[t] += s[t+st]; __syncthreads(); }
  if (t == 0) *flag = (s[0] < 2048) ? 1 : 0;
}

// ---------------- bf16 conversion of node_feats ----------------
__global__ void k_cvt(const void* __restrict__ in, u16* __restrict__ out, const int* __restrict__ dflag)
{
  int isbf = *dflag;
  size_t i = ((size_t)blockIdx.x*256 + threadIdx.x)*8;
  *(uint4*)&out[i] = load8bf(in, i, isbf);
}

// ---------------- weight convert + concat -> bf16 pool ----------------
// layout: [0,196608) init_node_w | per l at 196608+l*393216:
//   [0,65536) lin_l_w[l] | [65536,131072) lin_r_w[l] | [131072,262144) mlp_w1[l] | [262144,393216) mlp_w2[l]
__global__ void k_wcvt(const void* __restrict__ lw, const void* __restrict__ rw,
                       const void* __restrict__ w1, const void* __restrict__ w2,
                       const void* __restrict__ iw, u16* __restrict__ wall,
                       const int* __restrict__ dflag)
{
  int isbf = *dflag;
  size_t i = ((size_t)blockIdx.x*256 + threadIdx.x)*8;   // total 983040 elems
  const void* src; size_t off;
  if (i < 196608) { src = iw; off = i; }
  else {
    size_t j = i - 196608;
    size_t l = j / 393216; j -= l*393216;
    if (j < 65536)       { src = lw; off = l*65536 + j; }
    else if (j < 131072) { src = rw; off = l*65536 + (j - 65536); }
    else if (j < 262144) { src = w1; off = l*131072 + (j - 131072); }
    else                 { src = w2; off = l*131072 + (j - 262144); }
  }
  *(uint4*)&wall[i] = load8bf(src, off, isbf);
}

// ---------------- 2-phase pipelined GEMM, frag-order LDS via global_load_lds ----------------
// Block = 64 rows x (64*NJ) cols, 4 waves; wave w: all 64 rows x NJ*16 cols.
// A-frags shared by all waves -> As[frag i][lane][8] (conflict-free b128 reads).
// Wave w stages A-frag w and B-frags NJ*w..NJ*w+NJ-1 each k-step (global_load_lds,
// per-lane global src, linear LDS dest). Double-buffered, one barrier per k-step.
// CFMT: 0 fp32 C, 1 bf16 C, 2 both (C fp32 + C2 bf16). ACT 1 = gelu.
template<int KK, int NJ, int ACT, int CFMT>
__global__ __launch_bounds__(256)
void mg3(const u16* __restrict__ A, const u16* __restrict__ B,
         const void* __restrict__ bias1, const void* __restrict__ bias2,
         size_t bioff, int nsplit, int has_bias,
         void* __restrict__ C, void* __restrict__ C2, int N,
         const int* __restrict__ dflag)
{
  constexpr int NIT = KK/32;
  constexpr int NBF = 4*NJ;
  __shared__ u16 As[2][4][512];
  __shared__ u16 Bs[2][NBF][512];
  int isbf = *dflag;
  int t = threadIdx.x;
  int w = t>>6, lane = t&63, l4 = lane&15, quad = lane>>4;
  int bm = blockIdx.y*64, bn = blockIdx.x*(64*NJ);

  const u16* gA = A + (size_t)(bm + w*16 + l4)*KK + quad*8;
  const u16* gB[NJ];
  #pragma unroll
  for (int j=0;j<NJ;++j)
    gB[j] = B + (size_t)(bn + (NJ*w + j)*16 + l4)*KK + quad*8;

  f4v acc[4][NJ];
  f4v zero = {0.f,0.f,0.f,0.f};
  #pragma unroll
  for (int i=0;i<4;++i)
    #pragma unroll
    for (int j=0;j<NJ;++j) acc[i][j] = zero;

  // prologue: stage k-step 0 into buf 0
  gload16(gA, &As[0][w][0]);
  #pragma unroll
  for (int j=0;j<NJ;++j) gload16(gB[j], &Bs[0][NJ*w + j][0]);
  __syncthreads();

  int buf = 0;
  for (int it = 0; it < NIT; ++it) {
    if (it + 1 < NIT) {
      int k0 = (it+1)*32;
      gload16(gA + k0, &As[buf^1][w][0]);
      #pragma unroll
      for (int j=0;j<NJ;++j) gload16(gB[j] + k0, &Bs[buf^1][NJ*w + j][0]);
    }
    s8v a[4], b[NJ];
    #pragma unroll
    for (int i=0;i<4;++i) a[i] = *(const s8v*)&As[buf][i][lane*8];
    #pragma unroll
    for (int j=0;j<NJ;++j) b[j] = *(const s8v*)&Bs[buf][NJ*w + j][lane*8];
    #pragma unroll
    for (int i=0;i<4;++i)
      #pragma unroll
      for (int j=0;j<NJ;++j)
        acc[i][j] = __builtin_amdgcn_mfma_f32_16x16x32_bf16(a[i], b[j], acc[i][j], 0,0,0);
    __syncthreads();   // drains vmcnt(0): next buffer staged; LDS reads of this buffer done
    buf ^= 1;
  }

  // ---- epilogue ----
  #pragma unroll
  for (int i=0;i<4;++i)
    #pragma unroll
    for (int j=0;j<NJ;++j) {
      int cj = bn + (NJ*w + j)*16 + l4;
      float bvs = 0.f;
      if (has_bias) bvs = (cj < nsplit) ? ldf(bias1, bioff + cj, isbf)
                                        : ldf(bias2, bioff + cj - nsplit, isbf);
      #pragma unroll
      for (int r=0;r<4;++r) {
        int row = bm + i*16 + quad*4 + r;
        float v = acc[i][j][r] + bvs;
        if (ACT==1) v = gelu_f(v);
        if (CFMT==1) ((u16*)C)[(size_t)row*N + cj] = f2bf(v);
        else {
          ((float*)C)[(size_t)row*N + cj] = v;
          if (CFMT==2) ((u16*)C2)[(size_t)row*N + cj] = f2bf(v);
        }
      }
    }
}

// ---------------- CSR build ----------------
__global__ void k_count(const int* __restrict__ dst, int* __restrict__ deg)
{
  int e = blockIdx.x*256 + threadIdx.x;
  if (e >= ET) return;
  int d = (e < EE) ? dst[e] : (e - EE);
  atomicAdd(&deg[d], 1);
}

__global__ void k_scan(const int* __restrict__ deg, int* __restrict__ rowstart)
{
  __shared__ int csum[256];
  int t = threadIdx.x;
  int s = 0;
  for (int i=0;i<64;i++) s += deg[t*64+i];
  csum[t] = s;
  __syncthreads();
  if (t == 0) {
    int r = 0;
    for (int i=0;i<256;i++){ int v = csum[i]; csum[i] = r; r += v; }
    rowstart[NN] = r;
  }
  __syncthreads();
  int b = csum[t];
  for (int i=0;i<64;i++){ rowstart[t*64+i] = b; b += deg[t*64+i]; }
}

// also emit src/dst per CSR slot so hot kernels skip the csr->edge_index indirection
__global__ void k_scatter(const int* __restrict__ src, const int* __restrict__ dst,
                          const int* __restrict__ rowstart,
                          int* __restrict__ fill, int* __restrict__ csr,
                          int* __restrict__ srcc, int* __restrict__ dstc)
{
  int e = blockIdx.x*256 + threadIdx.x;
  if (e >= ET) return;
  int d  = (e < EE) ? dst[e] : (e - EE);
  int sv = (e < EE) ? src[e] : (e - EE);
  int pos = rowstart[d] + atomicAdd(&fill[d], 1);
  csr[pos]  = e;
  srcc[pos] = sv;
  dstc[pos] = d;
}

__global__ void k_loopmean(const int* __restrict__ csr, const int* __restrict__ rowstart,
                           const void* __restrict__ edge_attr, u16* __restrict__ loopmean,
                           const int* __restrict__ dflag)
{
  int isbf = *dflag;
  int n = blockIdx.x, j = threadIdx.x;   // 64 threads
  int s = rowstart[n], e1 = rowstart[n+1];
  float sum = 0.f; int cnt = 0;
  for (int p = s; p < e1; ++p) {
    int eid = csr[p];
    if (eid < EE) { sum += ldf(edge_attr, (size_t)eid*64 + j, isbf); cnt++; }
  }
  loopmean[(size_t)n*64 + j] = f2bf(sum / (float)max(cnt, 1));
}

// Wc[l] = lin_edge_w[l] ([256,128]) @ init_edge_w ([128,64]) -> [L,256,64] bf16
__global__ void k_wc(const void* __restrict__ We, const void* __restrict__ iew,
                     u16* __restrict__ Wcb, const int* __restrict__ dflag)
{
  int isbf = *dflag;
  int idx = blockIdx.x*256 + threadIdx.x;    // 32768
  int j = idx & 63, c = (idx >> 6) & 255, l = idx >> 14;
  float s = 0.f;
  for (int k=0;k<128;k++) s += ldf(We, ((size_t)l*256 + c)*128 + k, isbf) * ldf(iew, (size_t)k*64 + j, isbf);
  Wcb[idx] = f2bf(s);
}

// ---------------- edge-parallel logits in CSR (dst-sorted) order ----------------
__global__ __launch_bounds__(256)
void k_elogits(const int* __restrict__ csr, const int* __restrict__ srcc, const int* __restrict__ dstc,
               const u16* __restrict__ Wcb, const u16* __restrict__ xlr,
               const void* __restrict__ edge_attr, const u16* __restrict__ loopmean,
               const void* __restrict__ att, size_t att_off,
               float* __restrict__ logits, const int* __restrict__ dflag)
{
  int isbf = *dflag;
  __shared__ u16 WcF[32*64*8];    // 32 A-frags x 64 lanes x 8 bf16 (frag-order, conflict-free b128)
  __shared__ u16 attr_s[64*72];   // 64 edges x 64ch, stride 72
  __shared__ float satt[256];
  __shared__ int ssrc[64], sdst[64];

  int t = threadIdx.x;
  int w = t>>6, lane = t&63, l4 = lane&15, quad = lane>>4;

  satt[t] = ldf(att, att_off + t, isbf);
  #pragma unroll
  for (int f = 0; f < 8; ++f) {
    int fr = w + f*4;              // 0..31
    int i = fr >> 1, ks = fr & 1;
    *(uint4*)&WcF[(fr*64 + lane)*8] = *(const uint4*)&Wcb[(size_t)(16*i + l4)*64 + ks*32 + quad*8];
  }

  f4v zero = {0.f,0.f,0.f,0.f};
  for (int tile = blockIdx.x; tile < NTILES; tile += gridDim.x) {
    int e0 = tile*64;              // CSR position base
    __syncthreads();
    if (t < 64) {
      ssrc[t] = srcc[e0 + t];
      sdst[t] = dstc[e0 + t];
    }
    {
      int er = t >> 2, part = t & 3;
      int eid = csr[e0 + er];      // 4 threads/edge -> broadcast load
      uint4 v0, v1;
      if (eid < EE) {
        v0 = load8bf(edge_attr, (size_t)eid*64 + part*16,     isbf);
        v1 = load8bf(edge_attr, (size_t)eid*64 + part*16 + 8, isbf);
      } else {
        v0 = *(const uint4*)&loopmean[(size_t)(eid-EE)*64 + part*16];
        v1 = *(const uint4*)&loopmean[(size_t)(eid-EE)*64 + part*16 + 8];
      }
      *(uint4*)&attr_s[er*72 + part*16]     = v0;
      *(uint4*)&attr_s[er*72 + part*16 + 8] = v1;
    }
    __syncthreads();

    s8v b0 = *(const s8v*)&attr_s[(w*16 + l4)*72 + quad*8];
    s8v b1 = *(const s8v*)&attr_s[(w*16 + l4)*72 + 32 + quad*8];
    f4v acc[16];
    #pragma unroll
    for (int i=0;i<16;++i){
      s8v a0 = *(const s8v*)&WcF[((2*i  )*64 + lane)*8];
      s8v a1 = *(const s8v*)&WcF[((2*i+1)*64 + lane)*8];
      acc[i] = __builtin_amdgcn_mfma_f32_16x16x32_bf16(a0, b0, zero, 0,0,0);
      acc[i] = __builtin_amdgcn_mfma_f32_16x16x32_bf16(a1, b1, acc[i], 0,0,0);
    }

    int me = w*16 + l4;
    int sn = ssrc[me], dn = sdst[me];
    float ph[8] = {0.f,0.f,0.f,0.f,0.f,0.f,0.f,0.f};
    #pragma unroll
    for (int i=0;i<16;++i){
      uint2 xlv = *(const uint2*)&xlr[(size_t)sn*512 +       i*16 + quad*4];
      uint2 xrv = *(const uint2*)&xlr[(size_t)dn*512 + 256 + i*16 + quad*4];
      float4 av = *(const float4*)&satt[i*16 + quad*4];
      float m0 = acc[i][0] + bfu((u16)(xlv.x & 0xffff)) + bfu((u16)(xrv.x & 0xffff));
      float m1 = acc[i][1] + bfu((u16)(xlv.x >> 16))    + bfu((u16)(xrv.x >> 16));
      float m2 = acc[i][2] + bfu((u16)(xlv.y & 0xffff)) + bfu((u16)(xrv.y & 0xffff));
      float m3 = acc[i][3] + bfu((u16)(xlv.y >> 16))    + bfu((u16)(xrv.y >> 16));
      float g0 = fmaxf(m0, 0.2f*m0), g1 = fmaxf(m1, 0.2f*m1);
      float g2 = fmaxf(m2, 0.2f*m2), g3 = fmaxf(m3, 0.2f*m3);
      ph[i>>1] += av.x*g0 + av.y*g1 + av.z*g2 + av.w*g3;
    }
    #pragma unroll
    for (int h=0;h<8;++h){
      ph[h] += __shfl_xor(ph[h], 16);
      ph[h] += __shfl_xor(ph[h], 32);
    }
    if (quad == 0){
      float4 lo = {ph[0], ph[1], ph[2], ph[3]};
      float4 hi = {ph[4], ph[5], ph[6], ph[7]};
      *(float4*)&logits[(size_t)(e0 + me)*8]     = lo;
      *(float4*)&logits[(size_t)(e0 + me)*8 + 4] = hi;
    }
  }
}

// ---------------- one wave per node: online softmax + aggregate + bias + residual + LN1 ----------------
__global__ __launch_bounds__(256)
void k_aggln(const int* __restrict__ srcc, const int* __restrict__ rowstart,
             const float* __restrict__ logits, const u16* __restrict__ xlr, const float* __restrict__ xbuf,
             const void* __restrict__ gat_bias, const void* __restrict__ ln1g, const void* __restrict__ ln1b,
             size_t poff, float* __restrict__ hbuf, u16* __restrict__ hbufb, const int* __restrict__ dflag)
{
  int isbf = *dflag;
  int lane = threadIdx.x & 63, wid = threadIdx.x >> 6;
  int n = blockIdx.x*4 + wid;
  int s = rowstart[n], deg = rowstart[n+1] - s;
  int myh = lane >> 3;                       // head of channels 4*lane..4*lane+3
  float mrun = -3.0e38f, lrun = 0.f;
  float a0=0.f, a1=0.f, a2=0.f, a3=0.f;

  for (int c0 = 0; c0 < deg; c0 += 64) {
    int idx = s + c0 + lane; if (idx >= ET) idx = ET-1;
    int sv = srcc[idx];
    int lim = min(64, deg - c0);
    size_t lbase = (size_t)(s + c0)*8 + myh;
    for (int j = 0; j < lim; ++j) {
      int sn  = __shfl(sv, j);
      float lg = logits[lbase + (size_t)j*8];
      uint2 xv = *(const uint2*)&xlr[(size_t)sn*512 + 4*lane];
      float mn = fmaxf(mrun, lg);
      float sc = __expf(mrun - mn);
      float wv = __expf(lg - mn);
      mrun = mn;
      lrun = lrun*sc + wv;
      a0 = a0*sc + wv*bfu((u16)(xv.x & 0xffff));
      a1 = a1*sc + wv*bfu((u16)(xv.x >> 16));
      a2 = a2*sc + wv*bfu((u16)(xv.y & 0xffff));
      a3 = a3*sc + wv*bfu((u16)(xv.y >> 16));
    }
  }
  float inv = 1.f/(lrun + 1e-16f);
  int c = 4*lane;
  float4 res = *(const float4*)&xbuf[(size_t)n*256 + c];
  float o0 = a0*inv + ldf(gat_bias, poff+c+0, isbf) + res.x;
  float o1 = a1*inv + ldf(gat_bias, poff+c+1, isbf) + res.y;
  float o2 = a2*inv + ldf(gat_bias, poff+c+2, isbf) + res.z;
  float o3 = a3*inv + ldf(gat_bias, poff+c+3, isbf) + res.w;

  float v = o0+o1+o2+o3;
  #pragma unroll
  for (int off=1; off<64; off<<=1) v += __shfl_xor(v, off);
  float mu = v * (1.f/256.f);
  float d0=o0-mu, d1=o1-mu, d2=o2-mu, d3=o3-mu;
  float v2 = d0*d0+d1*d1+d2*d2+d3*d3;
  #pragma unroll
  for (int off=1; off<64; off<<=1) v2 += __shfl_xor(v2, off);
  float wn = rsqrtf(v2*(1.f/256.f) + 1e-5f);
  float4 outv;
  outv.x = d0*wn*ldf(ln1g, poff+c+0, isbf) + ldf(ln1b, poff+c+0, isbf);
  outv.y = d1*wn*ldf(ln1g, poff+c+1, isbf) + ldf(ln1b, poff+c+1, isbf);
  outv.z = d2*wn*ldf(ln1g, poff+c+2, isbf) + ldf(ln1b, poff+c+2, isbf);
  outv.w = d3*wn*ldf(ln1g, poff+c+3, isbf) + ldf(ln1b, poff+c+3, isbf);
  *(float4*)&hbuf[(size_t)n*256 + c] = outv;
  uint2 hb;
  hb.x = (unsigned)f2bf(outv.x) | ((unsigned)f2bf(outv.y)<<16);
  hb.y = (unsigned)f2bf(outv.z) | ((unsigned)f2bf(outv.w)<<16);
  *(uint2*)&hbufb[(size_t)n*256 + c] = hb;
}

// ---------------- residual + LN2 -> xbuf (fp32 + bf16) ----------------
__global__ __launch_bounds__(256)
void k_ln_add(const float* __restrict__ a, const u16* __restrict__ b2,
              const void* __restrict__ gg, const void* __restrict__ bb, size_t poff,
              float* __restrict__ out, u16* __restrict__ outb, const int* __restrict__ dflag)
{
  int isbf = *dflag;
  int n = blockIdx.x, t = threadIdx.x;
  __shared__ float r[256];
  float x = a[(size_t)n*256 + t] + bfu(b2[(size_t)n*256 + t]);
  r[t] = x; __syncthreads();
  for (int st = 128; st > 0; st >>= 1) { if (t < st) r[t] += r[t+st]; __syncthreads(); }
  float mu = r[0] * (1.f/256.f);
  __syncthreads();
  float d = x - mu;
  r[t] = d*d; __syncthreads();
  for (int st = 128; st > 0; st >>= 1) { if (t < st) r[t] += r[t+st]; __syncthreads(); }
  float var = r[0] * (1.f/256.f);
  float o = d * rsqrtf(var + 1e-5f) * ldf(gg, poff + t, isbf) + ldf(bb, poff + t, isbf);
  out[(size_t)n*256 + t] = o;
  outb[(size_t)n*256 + t] = f2bf(o);
}

__global__ void k_out(const float* __restrict__ x, void* __restrict__ out, const int* __restrict__ dflag)
{
  int isbf = *dflag;
  int i = blockIdx.x*256 + threadIdx.x;
  if (isbf) ((u16*)out)[i] = f2bf(x[i]);
  else      ((float*)out)[i] = x[i];
}

extern "C" void kernel_launch(void* const* d_in, const int* in_sizes, int n_in,
                              void* d_out, int out_size, void* d_ws, size_t ws_size,
                              hipStream_t stream)
{
  const void* node_feats = d_in[0];
  const int*  edge_index = (const int*)d_in[1];
  const void* edge_attr  = d_in[2];
  const void* init_node_w= d_in[3];
  const void* init_edge_w= d_in[4];
  const void* lin_l_w    = d_in[5];
  const void* lin_l_b    = d_in[6];
  const void* lin_r_w    = d_in[7];
  const void* lin_r_b    = d_in[8];
  const void* lin_edge_w = d_in[9];
  const void* att        = d_in[10];
  const void* gat_bias   = d_in[11];
  const void* ln1_g      = d_in[12];
  const void* ln1_b      = d_in[13];
  const void* mlp_w1     = d_in[14];
  const void* mlp_w2     = d_in[15];
  const void* ln2_g      = d_in[16];
  const void* ln2_b      = d_in[17];

  const int* srcp = edge_index;
  const int* dstp = edge_index + EE;

  char* p = (char*)d_ws;
  auto alloc = [&](size_t bytes) { void* r = (void*)p; p += (bytes + 255) & ~(size_t)255; return r; };
  int*   dflag   = (int*)alloc(256);
  int*   deg     = (int*)alloc((size_t)NN*4);
  int*   rowstart= (int*)alloc((size_t)(NN+1)*4);
  int*   fill    = (int*)alloc((size_t)NN*4);
  int*   csr     = (int*)alloc((size_t)ET*4);
  int*   srcc    = (int*)alloc((size_t)ET*4);
  int*   dstc    = (int*)alloc((size_t)ET*4);
  u16*   Wcb     = (u16*)alloc((size_t)2*256*64*2);
  u16*   loopmean= (u16*)alloc((size_t)NN*64*2);
  u16*   wall    = (u16*)alloc((size_t)983040*2);   // bf16 weight pool
  // logits + hbuf allocated contiguously; nfb (24 MB, init-only) aliases their span
  float* logits  = (float*)alloc((size_t)ET*8*4);           // 8.9 MB
  float* hbuf    = (float*)alloc((size_t)NN*256*4);         // 16 MB
  float* xbuf    = (float*)alloc((size_t)NN*256*4);
  u16*   xbufb   = (u16*)alloc((size_t)NN*256*2);
  u16*   hbufb   = (u16*)alloc((size_t)NN*256*2);
  u16*   xlr     = (u16*)alloc((size_t)NN*512*2);  // xl = cols 0..255, xr = cols 256..511
  u16*   nfb     = (u16*)logits;    // [NN,768] bf16, dead before logits/hbuf are written
  u16*   ymid    = xlr;             // [NN,512] bf16 alias (xlr dead at MLP time)
  u16*   y2      = (u16*)d_out;     // bf16 scratch; final k_out overwrites

  u16* Wn = wall;                   // [256][768]

  hipMemsetAsync(deg,  0, (size_t)NN*4, stream);
  hipMemsetAsync(fill, 0, (size_t)NN*4, stream);

  k_detect <<<1, 256, 0, stream>>>(node_feats, dflag);

  k_count  <<<(ET+255)/256, 256, 0, stream>>>(dstp, deg);
  k_scan   <<<1, 256, 0, stream>>>(deg, rowstart);
  k_scatter<<<(ET+255)/256, 256, 0, stream>>>(srcp, dstp, rowstart, fill, csr, srcc, dstc);
  k_loopmean<<<NN, 64, 0, stream>>>(csr, rowstart, edge_attr, loopmean, dflag);
  k_wc     <<<128, 256, 0, stream>>>(lin_edge_w, init_edge_w, Wcb, dflag);
  k_wcvt   <<<480, 256, 0, stream>>>(lin_l_w, lin_r_w, mlp_w1, mlp_w2, init_node_w, wall, dflag);

  // node_feats -> bf16
  k_cvt<<<(NN*768)/(8*256), 256, 0, stream>>>(node_feats, nfb, dflag);
  // x = node_feats @ init_node_w.T  (fp32 xbuf + bf16 xbufb)
  mg3<768,1,0,2><<<dim3(4, NN/64), 256, 0, stream>>>(nfb, Wn, nullptr, nullptr, 0, 1<<29, 0,
                                                     xbuf, xbufb, 256, dflag);

  for (int l = 0; l < 2; ++l) {
    size_t bo = (size_t)l*256;
    u16* Wlr = wall + 196608 + (size_t)l*393216;   // [512][256]: rows 0-255 lin_l, 256-511 lin_r
    u16* W1  = Wlr + 131072;                       // [512][256]
    u16* W2  = Wlr + 262144;                       // [256][512]
    // xlr = [x@Wl^T + bl | x@Wr^T + br]
    mg3<256,2,0,1><<<dim3(4, NN/64), 256, 0, stream>>>(xbufb, Wlr, lin_l_b, lin_r_b, bo, 256, 1,
                                                       xlr, nullptr, 512, dflag);
    k_elogits<<<768, 256, 0, stream>>>(csr, srcc, dstc, Wcb + (size_t)l*256*64, xlr,
                                       edge_attr, loopmean, att, (size_t)l*256, logits, dflag);
    k_aggln<<<NN/4, 256, 0, stream>>>(srcc, rowstart, logits, xlr, xbuf,
                                      gat_bias, ln1_g, ln1_b, bo, hbuf, hbufb, dflag);
    mg3<256,2,1,1><<<dim3(4, NN/64), 256, 0, stream>>>(hbufb, W1, nullptr, nullptr, 0, 1<<29, 0,
                                                       ymid, nullptr, 512, dflag);
    mg3<512,1,0,1><<<dim3(4, NN/64), 256, 0, stream>>>(ymid, W2, nullptr, nullptr, 0, 1<<29, 0,
                                                       y2, nullptr, 256, dflag);
    k_ln_add<<<NN, 256, 0, stream>>>(hbuf, y2, ln2_g, ln2_b, bo, xbuf, xbufb, dflag);
  }

  k_out<<<(NN*256)/256, 256, 0, stream>>>(xbuf, d_out, dflag);
}